// Round 2
// baseline (14245.891 us; speedup 1.0000x reference)
//
#include <hip/hip_runtime.h>

// GRU scan: T=512, B=256, D=512, H=512.
// det_kernel: detect resets dtype (int32 vs byte-bool) -> flag in ws.
// rmask_kernel: normalize resets -> fp32 mask [T*B].
// convert_kernel: WiT/WhT (f16, [n][k]), hbuf0 = (f16)h0.
// scan_kernel: 256 persistent blocks = 16 batch-groups x 16 col-tiles.
//   Per block: 16 rows x 32 cols. Waves: 0=r,1=z(+combine/store/arrive),2=n,
//   3=x-prefetch. Wi AND Wh fragments resident in VGPRs (256 VGPR/wave);
//   gi[t+1] computed from LDS-staged x before the group-barrier poll.

#define T_STEPS 512
#define BATCH   256
#define HID     512

typedef _Float16 half8 __attribute__((ext_vector_type(8)));
typedef float    f32x4 __attribute__((ext_vector_type(4)));

__device__ __forceinline__ float sigmoid_f(float x) { return 1.f / (1.f + __expf(-x)); }
__device__ __forceinline__ float tanh_f(float x) {
    float e = __expf(2.f * x);
    return 1.f - 2.f / (e + 1.f);
}
__device__ __forceinline__ half8 cvt8(float4 a, float4 b) {
    half8 h;
    h[0] = (_Float16)a.x; h[1] = (_Float16)a.y; h[2] = (_Float16)a.z; h[3] = (_Float16)a.w;
    h[4] = (_Float16)b.x; h[5] = (_Float16)b.y; h[6] = (_Float16)b.z; h[7] = (_Float16)b.w;
    return h;
}

// --------------------------------------------------------------------------
// resets dtype detector: int32 0/1 values have all bytes at idx%4!=0 == 0;
// byte-bool random 0/1 does not. Scans the first T*B bytes (safe for both).
// --------------------------------------------------------------------------
__global__ void __launch_bounds__(256) det_kernel(
    const unsigned char* __restrict__ r, unsigned int* flag)
{
    int i = blockIdx.x * 256 + threadIdx.x;   // grid 512 -> 131072 bytes
    unsigned int v = ((i & 3) && r[i]) ? 1u : 0u;
    if (__any(v)) { if ((threadIdx.x & 63) == 0) atomicOr(flag, 1u); }
}

__global__ void __launch_bounds__(256) rmask_kernel(
    const void* __restrict__ rsets, const unsigned int* __restrict__ flag,
    float* __restrict__ rmask)
{
    int i = blockIdx.x * 256 + threadIdx.x;   // grid 512
    int v = (*flag) ? (int)((const unsigned char*)rsets)[i]
                    : ((const int*)rsets)[i];
    rmask[i] = v ? 1.f : 0.f;
}

// --------------------------------------------------------------------------
// WiT[n][k] = Wi[k][n] (n<1536,k<512); WhT[n][k] = [Whrz|Whn]^T; hbuf0=(f16)h0
// grid 6656 x 256
// --------------------------------------------------------------------------
__global__ void __launch_bounds__(256) convert_kernel(
    const float* __restrict__ Wi, const float* __restrict__ Whrz,
    const float* __restrict__ Whn, const float* __restrict__ h0,
    _Float16* __restrict__ WiT, _Float16* __restrict__ WhT,
    _Float16* __restrict__ hbuf)
{
    const int bid = blockIdx.x, tid = threadIdx.x;
    if (bid < 3072) {
        int j = bid * 256 + tid;           // j = n*512 + k
        int n = j >> 9, k = j & 511;
        WiT[j] = (_Float16)Wi[k * 1536 + n];
    } else if (bid < 6144) {
        int j = (bid - 3072) * 256 + tid;
        int n = j >> 9, k = j & 511;
        float v = (n < 1024) ? Whrz[k * 1024 + n] : Whn[k * 512 + (n - 1024)];
        WhT[j] = (_Float16)v;
    } else {
        int j = (bid - 6144) * 256 + tid;  // 512 blocks * 256 = 131072
        hbuf[j] = (_Float16)h0[j];
    }
}

// --------------------------------------------------------------------------
// scan
// --------------------------------------------------------------------------
__global__ void __launch_bounds__(256, 1) scan_kernel(
    const float* __restrict__ X, const _Float16* __restrict__ WiT,
    const _Float16* __restrict__ WhT, const float* __restrict__ bi,
    const float* __restrict__ bhn, const float* __restrict__ rmask,
    _Float16* __restrict__ hbuf, unsigned int* cnt, float* __restrict__ out)
{
    const int bid = blockIdx.x;
    const int g = bid >> 4;          // batch group 0..15 (rows 16g..16g+15)
    const int c = bid & 15;          // col tile 0..15 (H cols 32c..32c+31)
    const int tid = threadIdx.x;
    const int wave = tid >> 6;
    const int lane = tid & 63;
    const int l15 = lane & 15;
    const int q = lane >> 4;

    __shared__ __align__(16) _Float16 xl[2][16][520];
    __shared__ __align__(16) _Float16 hl[16][520];
    __shared__ float r_lds[16][33];
    __shared__ float n_lds[16][33];

    half8 bwh[2][16], bwi[2][16];
    float biv[2] = {0.f, 0.f}, bhnv[2] = {0.f, 0.f};

    if (wave < 3) {
        // B-frags: lane holds B[k = ck*32 + q*8 + j][n = l15]; source is [n][k]
#pragma unroll
        for (int nf = 0; nf < 2; nf++) {
            const int nrow = wave * 512 + 32 * c + nf * 16 + l15;
#pragma unroll
            for (int ck = 0; ck < 16; ck++) {
                bwh[nf][ck] = *(const half8*)&WhT[(size_t)nrow * 512 + ck * 32 + q * 8];
                bwi[nf][ck] = *(const half8*)&WiT[(size_t)nrow * 512 + ck * 32 + q * 8];
            }
            biv[nf] = bi[wave * 512 + 32 * c + nf * 16 + l15];
        }
        if (wave == 2) {
            bhnv[0] = bhn[32 * c + l15];
            bhnv[1] = bhn[32 * c + 16 + l15];
        }
    }
    // stage x[0] -> xl[0] (all waves; 16 rows x 512 f32)
    {
        const float* xsrc = X + (size_t)(16 * g) * 512;
#pragma unroll
        for (int it = 0; it < 4; it++) {
            int fidx = it * 2048 + tid * 8;
            int row = fidx >> 9, col = fidx & 511;
            float4 a = *(const float4*)(xsrc + row * 512 + col);
            float4 b = *(const float4*)(xsrc + row * 512 + col + 4);
            *(half8*)&xl[0][row][col] = cvt8(a, b);
        }
    }
    __syncthreads();

    f32x4 gcur[2], gn[2], acc[2];
    float zv[2][4], hpv[2][4];
    const f32x4 zero4 = {0.f, 0.f, 0.f, 0.f};
    const half8 z8 = {0, 0, 0, 0, 0, 0, 0, 0};

    if (wave < 3) {   // gcur = gi[0] (no bias)
        gcur[0] = zero4; gcur[1] = zero4;
#pragma unroll
        for (int ck = 0; ck < 16; ck++) {
            half8 a = *(const half8*)&xl[0][l15][ck * 32 + q * 8];
            gcur[0] = __builtin_amdgcn_mfma_f32_16x16x32_f16(a, bwi[0][ck], gcur[0], 0, 0, 0);
            gcur[1] = __builtin_amdgcn_mfma_f32_16x16x32_f16(a, bwi[1][ck], gcur[1], 0, 0, 0);
        }
    } else {          // wave3: stage x[1] -> xl[1]
        const float* xsrc = X + (size_t)(256 + 16 * g) * 512;
#pragma unroll
        for (int it = 0; it < 16; it++) {
            float4 a = *(const float4*)(xsrc + it * 512 + lane * 8);
            float4 b = *(const float4*)(xsrc + it * 512 + lane * 8 + 4);
            *(half8*)&xl[1][it][lane * 8] = cvt8(a, b);
        }
    }
    __syncthreads();

#pragma unroll 1
    for (int t = 0; t < T_STEPS; t++) {
        const int buf = t & 1;
        // wave3 pre-B1: stage x[t+2] -> xl[buf] (consumed at step t+1)
        if (wave == 3 && t + 2 < T_STEPS) {
            const float* xsrc = X + (size_t)((t + 2) * 256 + 16 * g) * 512;
#pragma unroll
            for (int it = 0; it < 16; it++) {
                float4 a = *(const float4*)(xsrc + it * 512 + lane * 8);
                float4 b = *(const float4*)(xsrc + it * 512 + lane * 8 + 4);
                *(half8*)&xl[buf][it][lane * 8] = cvt8(a, b);
            }
        }
        __syncthreads();   // B1

        // gi[t+1] off the critical path (xl[1-buf] = x[t+1])
        if (wave < 3 && t + 1 < T_STEPS) {
            gn[0] = zero4; gn[1] = zero4;
#pragma unroll
            for (int ck = 0; ck < 16; ck++) {
                half8 a = *(const half8*)&xl[1 - buf][l15][ck * 32 + q * 8];
                gn[0] = __builtin_amdgcn_mfma_f32_16x16x32_f16(a, bwi[0][ck], gn[0], 0, 0, 0);
                gn[1] = __builtin_amdgcn_mfma_f32_16x16x32_f16(a, bwi[1][ck], gn[1], 0, 0, 0);
            }
        }
        // group barrier: all 16 blocks of group g finished step t-1
        if (t > 0) {
            const unsigned int tgt = 16u * (unsigned int)t;
            while (__hip_atomic_load(cnt + g, __ATOMIC_ACQUIRE, __HIP_MEMORY_SCOPE_AGENT) < tgt)
                __builtin_amdgcn_s_sleep(2);
        }
        // stage masked h -> hl (all waves; 16 rows x 512 f16)
        {
            const _Float16* hsrc = hbuf + (size_t)buf * (BATCH * HID) + (size_t)(16 * g) * 512;
#pragma unroll
            for (int it = 0; it < 4; it++) {
                int hidx = it * 2048 + tid * 8;
                int row = hidx >> 9, col = hidx & 511;
                half8 v = *(const half8*)(hsrc + row * 512 + col);
                float rst = rmask[t * 256 + 16 * g + row];
                v = (rst != 0.f) ? z8 : v;
                *(half8*)&hl[row][col] = v;
            }
        }
        __syncthreads();   // B2: hl ready

        if (wave < 3) {
            acc[0] = zero4; acc[1] = zero4;
#pragma unroll
            for (int ck = 0; ck < 16; ck++) {
                half8 a = *(const half8*)&hl[l15][ck * 32 + q * 8];
                acc[0] = __builtin_amdgcn_mfma_f32_16x16x32_f16(a, bwh[0][ck], acc[0], 0, 0, 0);
                acc[1] = __builtin_amdgcn_mfma_f32_16x16x32_f16(a, bwh[1][ck], acc[1], 0, 0, 0);
            }
            if (wave == 0) {
#pragma unroll
                for (int nf = 0; nf < 2; nf++)
#pragma unroll
                    for (int reg = 0; reg < 4; reg++) {
                        int row = q * 4 + reg, col = nf * 16 + l15;
                        r_lds[row][col] = sigmoid_f(gcur[nf][reg] + biv[nf] + acc[nf][reg]);
                    }
            } else if (wave == 1) {
#pragma unroll
                for (int nf = 0; nf < 2; nf++)
#pragma unroll
                    for (int reg = 0; reg < 4; reg++) {
                        int row = q * 4 + reg, col = nf * 16 + l15;
                        zv[nf][reg] = sigmoid_f(gcur[nf][reg] + biv[nf] + acc[nf][reg]);
                        hpv[nf][reg] = (float)hl[row][32 * c + col];   // masked h
                    }
            }
        }
        __syncthreads();   // B3: r_lds ready

        if (wave == 2) {
#pragma unroll
            for (int nf = 0; nf < 2; nf++)
#pragma unroll
                for (int reg = 0; reg < 4; reg++) {
                    int row = q * 4 + reg, col = nf * 16 + l15;
                    float hn = acc[nf][reg] + bhnv[nf];
                    n_lds[row][col] = tanh_f(gcur[nf][reg] + biv[nf] + r_lds[row][col] * hn);
                }
        }
        __syncthreads();   // B4: n_lds ready

        if (wave == 1) {
            _Float16* hdst = hbuf + (size_t)(1 - buf) * (BATCH * HID);
#pragma unroll
            for (int nf = 0; nf < 2; nf++)
#pragma unroll
                for (int reg = 0; reg < 4; reg++) {
                    int row = q * 4 + reg, col = nf * 16 + l15;
                    float nn = n_lds[row][col];
                    float z = zv[nf][reg];
                    float hnew = (1.f - z) * nn + z * hpv[nf][reg];
                    hdst[(size_t)(16 * g + row) * 512 + 32 * c + col] = (_Float16)hnew;
                    __builtin_nontemporal_store(hnew,
                        out + 131072 + ((size_t)t * 256 + 16 * g + row) * 512 + 32 * c + col);
                    if (t == T_STEPS - 1)
                        out[(size_t)(16 * g + row) * 512 + 32 * c + col] = hnew;
                }
            __threadfence();   // make h stores visible device-wide before arriving
            if (lane == 0)
                __hip_atomic_fetch_add(cnt + g, 1u, __ATOMIC_RELEASE, __HIP_MEMORY_SCOPE_AGENT);
        }
        if (wave < 3 && t + 1 < T_STEPS) { gcur[0] = gn[0]; gcur[1] = gn[1]; }
    }
}

// ---------------------------------------------------------------------------
extern "C" void kernel_launch(void* const* d_in, const int* in_sizes, int n_in,
                              void* d_out, int out_size, void* d_ws, size_t ws_size,
                              hipStream_t stream)
{
    (void)in_sizes; (void)n_in; (void)out_size; (void)ws_size;
    const float* h0   = (const float*)d_in[0];
    const float* X    = (const float*)d_in[1];
    const void*  rsts = d_in[2];
    const float* Wi   = (const float*)d_in[3];
    const float* bi   = (const float*)d_in[4];
    const float* Whrz = (const float*)d_in[5];
    const float* Whn  = (const float*)d_in[6];
    const float* bhn  = (const float*)d_in[7];
    float* out = (float*)d_out;
    char*  ws  = (char*)d_ws;

    // workspace layout (~4.2 MiB total)
    unsigned int* flag  = (unsigned int*)ws;                  // 4B
    unsigned int* cnt   = (unsigned int*)(ws + 256);          // 16 counters
    float*    rmask     = (float*)(ws + 1024);                // 131072 f32
    _Float16* WiT       = (_Float16*)(ws + 1024 + 524288);    // 1536*512 f16
    _Float16* WhT       = WiT + 1536 * 512;                   // 1536*512 f16
    _Float16* hbuf      = WhT + 1536 * 512;                   // 2 * 256*512 f16

    hipMemsetAsync(ws, 0, 1024, stream);                      // flag + counters
    det_kernel<<<512, 256, 0, stream>>>((const unsigned char*)rsts, flag);
    rmask_kernel<<<512, 256, 0, stream>>>(rsts, flag, rmask);
    convert_kernel<<<6656, 256, 0, stream>>>(Wi, Whrz, Whn, h0, WiT, WhT, hbuf);
    scan_kernel<<<256, 256, 0, stream>>>(X, WiT, WhT, bi, bhn, rmask, hbuf, cnt, out);
}